// Round 7
// baseline (394.213 us; speedup 1.0000x reference)
//
#include <hip/hip_runtime.h>
#include <math.h>

typedef __attribute__((ext_vector_type(8))) short bf16x8;
typedef __attribute__((ext_vector_type(4))) float f32x4;
typedef __attribute__((ext_vector_type(4))) unsigned short u16x4;

#define NB 64
#define NS 4096
#define NH 512
#define NE 1024
#define APITCH 80  // 64B bf16 K-row + 16B pad: conflict-free b128 frag reads

__device__ __forceinline__ unsigned short f2bf(float f) {
  unsigned int u = __float_as_uint(f);
  u += 0x7fffu + ((u >> 16) & 1u);
  return (unsigned short)(u >> 16);
}

__device__ __forceinline__ float fast_tanh(float x) {
  float e = __expf(2.0f * x);
  return 1.0f - 2.0f * __builtin_amdgcn_rcpf(e + 1.0f);
}

// ---- pack W (f32 [512][1024]) into MFMA B-fragment order, bf16 ----
// chunk c = ((w*32 + kb)*4 + ni); lane l's 16B = W[w*64+ni*16+(l&15)][kb*32+(l>>4)*8 .. +7]
__global__ __launch_bounds__(256) void prep_b_kernel(const float* __restrict__ W,
                                                     unsigned short* __restrict__ Bp) {
  const int t = blockIdx.x * 256 + threadIdx.x;  // 0..65535
  const int lane = t & 63;
  const int ni = (t >> 6) & 3;
  const int kb = (t >> 8) & 31;
  const int w = t >> 13;
  const int col = w * 64 + ni * 16 + (lane & 15);
  const int k0 = kb * 32 + (lane >> 4) * 8;
  const float* src = W + col * NE + k0;
  float4 a = *(const float4*)src;
  float4 b = *(const float4*)(src + 4);
  union { bf16x8 v; unsigned short u[8]; } p;
  p.u[0] = f2bf(a.x); p.u[1] = f2bf(a.y); p.u[2] = f2bf(a.z); p.u[3] = f2bf(a.w);
  p.u[4] = f2bf(b.x); p.u[5] = f2bf(b.y); p.u[6] = f2bf(b.z); p.u[7] = f2bf(b.w);
  *(bf16x8*)(Bp + (long long)t * 8) = p.v;
}

// ---- prep: dec[b,h] = decoder_output[b,:] . W_s_w[h,:] + W_s_b[h] + W_h_b[h] ----
__global__ __launch_bounds__(512) void prep_dec_kernel(const float* __restrict__ dec,
                                                       const float* __restrict__ Wsw,
                                                       const float* __restrict__ Wsb,
                                                       const float* __restrict__ Whb,
                                                       float* __restrict__ decb) {
  int b = blockIdx.x;
  int h = threadIdx.x;
  const float4* dr = (const float4*)(dec + b * NH);
  const float4* wr = (const float4*)(Wsw + h * NH);
  float sum = Wsb[h] + Whb[h];
#pragma unroll 8
  for (int i = 0; i < NH / 4; ++i) {
    float4 a = dr[i], w = wr[i];
    sum += a.x * w.x + a.y * w.y + a.z * w.z + a.w * w.w;
  }
  decb[b * NH + h] = sum;
}

// ---- main: enc-proj GEMM (bf16 MFMA) + bias + tanh + v-dot -> scores ----
// BM=64, BN=512, BK=32, 512 thr / 8 waves, 2 blocks/CU.
// 4-phase fine interleave (T3): phase p = {B(t+1)[p] issue | af[p] ds_read ->
// 4 MFMA (setprio) -> s_barrier}. A-write in phase 3; aNew 2 steps ahead.
// Compiler-counted vmcnt (raw s_barrier never drains); manual lgkm(0) only at
// phase-3 write fence.
__global__ __launch_bounds__(512, 4) void fused_main(const float* __restrict__ enc,
                                                     const unsigned short* __restrict__ Bp,
                                                     const float* __restrict__ decb,
                                                     const float* __restrict__ vw,
                                                     float* __restrict__ scores) {
  __shared__ __align__(16) char As[2][64 * APITCH];  // bf16 tiles, 2 x 5KB
  __shared__ float ssc[64];

  const int tid = threadIdx.x;
  const int lane = tid & 63;
  const int wave = tid >> 6;
  const int r15 = lane & 15;
  const int c4 = lane >> 4;
  const long long m0 = (long long)blockIdx.x * 64;

  if (tid < 64) ssc[tid] = 0.0f;

  // A staging: thread t -> row t>>3, f32-chunk t&7 (4 floats, coalesced 128B/row)
  const int arow = tid >> 3;
  const int achk = tid & 7;
  const float* aload = enc + (m0 + arow) * NE + achk * 4;
  const int awr = arow * APITCH + achk * 8;  // bf16 bytes

  const unsigned short* const bb = Bp + (long long)wave * 32 * 2048 + lane * 8;

  f32x4 acc[4][4];
#pragma unroll
  for (int mi = 0; mi < 4; ++mi)
#pragma unroll
    for (int ni = 0; ni < 4; ++ni) {
      f32x4 z = {0.f, 0.f, 0.f, 0.f};
      acc[mi][ni] = z;
    }

  // prologue: B(0)->bA; A(0)->cvt->buf0; A(1)->aCur
  bf16x8 bA[4], bB[4];
#pragma unroll
  for (int ni = 0; ni < 4; ++ni) bA[ni] = *(const bf16x8*)(bb + ni * 512);
  {
    float4 a0 = *(const float4*)(aload);
    unsigned int p0, p1;
    asm("v_cvt_pk_bf16_f32 %0, %1, %2" : "=v"(p0) : "v"(a0.x), "v"(a0.y));
    asm("v_cvt_pk_bf16_f32 %0, %1, %2" : "=v"(p1) : "v"(a0.z), "v"(a0.w));
    uint2 wv; wv.x = p0; wv.y = p1;
    *(uint2*)(&As[0][0] + awr) = wv;
  }
  float4 aCur = *(const float4*)(aload + 32);  // A(1)
  asm volatile("s_waitcnt lgkmcnt(0)" ::: "memory");
  __builtin_amdgcn_s_barrier();
  __builtin_amdgcn_sched_barrier(0);

#pragma unroll
  for (int t = 0; t < 32; ++t) {
    const char* Ab = &As[t & 1][0];
    const bf16x8* bpn = (const bf16x8*)(bb + (t + 1) * 2048);
    float4 aNew;
#pragma unroll
    for (int p = 0; p < 4; ++p) {
      // ---- mem-issue slice ----
      if (p == 0 && t < 30) aNew = *(const float4*)(aload + (t + 2) * 32);
      if (t < 31) {  // B(t+1)[p] -> opposite ping-pong buffer (static parity)
        if (t & 1) bA[p] = bpn[p * 64];
        else       bB[p] = bpn[p * 64];
      }
      // ---- A fragment p (one b128; compiler emits counted lgkm before MFMA) ----
      bf16x8 af = *(const bf16x8*)(Ab + (p * 16 + r15) * APITCH + c4 * 16);
      __builtin_amdgcn_s_setprio(1);
#pragma unroll
      for (int ni = 0; ni < 4; ++ni)
        acc[p][ni] = __builtin_amdgcn_mfma_f32_16x16x32_bf16(
            af, (t & 1) ? bB[ni] : bA[ni], acc[p][ni], 0, 0, 0);
      __builtin_amdgcn_s_setprio(0);
      if (p == 3) {
        if (t < 31) {  // write A(t+1) -> opposite buffer
          unsigned int w0, w1;
          asm("v_cvt_pk_bf16_f32 %0, %1, %2" : "=v"(w0) : "v"(aCur.x), "v"(aCur.y));
          asm("v_cvt_pk_bf16_f32 %0, %1, %2" : "=v"(w1) : "v"(aCur.z), "v"(aCur.w));
          uint2 wv; wv.x = w0; wv.y = w1;
          *(uint2*)(&As[(t & 1) ^ 1][0] + awr) = wv;
          aCur = aNew;
        }
        asm volatile("s_waitcnt lgkmcnt(0)" ::: "memory");
        __builtin_amdgcn_sched_barrier(0);
      }
      __builtin_amdgcn_s_barrier();  // phase rhythm; phase-3 also fences A-write
    }
  }

  // epilogue: x = tanh(acc + dec[b,h]); score += v[h]*x
  // C/D layout: col = lane&15 (n), row = (lane>>4)*4 + j (m)
  const int bidx = (int)(m0 >> 12);  // blockIdx / 64
  const float* decrow = decb + bidx * NH;
  float part[4][4];
#pragma unroll
  for (int mi = 0; mi < 4; ++mi)
#pragma unroll
    for (int j = 0; j < 4; ++j) part[mi][j] = 0.f;

#pragma unroll
  for (int ni = 0; ni < 4; ++ni) {
    int col = (wave << 6) + ni * 16 + r15;
    float vc = vw[col];
    float dc = decrow[col];
#pragma unroll
    for (int mi = 0; mi < 4; ++mi)
#pragma unroll
      for (int j = 0; j < 4; ++j)
        part[mi][j] += vc * fast_tanh(acc[mi][ni][j] + dc);
  }
#pragma unroll
  for (int off = 1; off < 16; off <<= 1)
#pragma unroll
    for (int mi = 0; mi < 4; ++mi)
#pragma unroll
      for (int j = 0; j < 4; ++j)
        part[mi][j] += __shfl_xor(part[mi][j], off, 64);

  if (r15 == 0) {
#pragma unroll
    for (int mi = 0; mi < 4; ++mi)
#pragma unroll
      for (int j = 0; j < 4; ++j)
        atomicAdd(&ssc[mi * 16 + c4 * 4 + j], part[mi][j]);
  }
  __syncthreads();
  if (tid < 64) scores[m0 + tid] = ssc[tid];
}

// ---- masked softmax over S per batch row ----
__global__ __launch_bounds__(1024) void softmax_kernel(const float* __restrict__ scores,
                                                       const int* __restrict__ mask,
                                                       float* __restrict__ out) {
  __shared__ float rmax[16];
  __shared__ float rsum[16];
  const int b = blockIdx.x;
  const int t = threadIdx.x;
  const int wid = t >> 6;
  const int ln = t & 63;
  const int base = b * NS;

  float s[4];
  int mk[4];
  float mx = -INFINITY;
#pragma unroll
  for (int i = 0; i < 4; ++i) {
    int idx = t + i * 1024;
    s[i] = scores[base + idx];
    mk[i] = mask[base + idx];
    if (mk[i]) mx = fmaxf(mx, s[i]);
  }
#pragma unroll
  for (int off = 1; off < 64; off <<= 1) mx = fmaxf(mx, __shfl_xor(mx, off, 64));
  if (ln == 0) rmax[wid] = mx;
  __syncthreads();
  float m2 = -INFINITY;
#pragma unroll
  for (int i = 0; i < 16; ++i) m2 = fmaxf(m2, rmax[i]);

  float e[4];
  float sum = 0.f;
#pragma unroll
  for (int i = 0; i < 4; ++i) {
    e[i] = mk[i] ? expf(s[i] - m2) : 0.f;
    sum += e[i];
  }
#pragma unroll
  for (int off = 1; off < 64; off <<= 1) sum += __shfl_xor(sum, off, 64);
  if (ln == 0) rsum[wid] = sum;
  __syncthreads();
  float tot = 0.f;
#pragma unroll
  for (int i = 0; i < 16; ++i) tot += rsum[i];
  float inv = 1.0f / tot;
#pragma unroll
  for (int i = 0; i < 4; ++i) {
    int idx = t + i * 1024;
    out[base + idx] = e[i] * inv;
  }
}

extern "C" void kernel_launch(void* const* d_in, const int* in_sizes, int n_in,
                              void* d_out, int out_size, void* d_ws, size_t ws_size,
                              hipStream_t stream) {
  const float* dec = (const float*)d_in[0];   // [64,512]
  const float* enc = (const float*)d_in[1];   // [64,4096,1024]
  const int* mask = (const int*)d_in[2];      // [64,4096]
  const float* Whw = (const float*)d_in[3];   // [512,1024]
  const float* Whb = (const float*)d_in[4];   // [512]
  const float* Wsw = (const float*)d_in[5];   // [512,512]
  const float* Wsb = (const float*)d_in[6];   // [512]
  const float* vw = (const float*)d_in[7];    // [1,512]
  float* out = (float*)d_out;                 // [64,4096]

  unsigned short* Bp = (unsigned short*)d_ws;                         // 1 MB packed W
  float* decb = (float*)((char*)d_ws + (1 << 20));                    // 128 KB
  float* scoresb = (float*)((char*)d_ws + (1 << 20) + (128 << 10));   // 1 MB

  prep_b_kernel<<<dim3(256), dim3(256), 0, stream>>>(Whw, Bp);
  prep_dec_kernel<<<dim3(64), dim3(512), 0, stream>>>(dec, Wsw, Wsb, Whb, decb);
  fused_main<<<dim3(4096), dim3(512), 0, stream>>>(enc, Bp, decb, vw, scoresb);
  softmax_kernel<<<dim3(64), dim3(1024), 0, stream>>>(scoresb, mask, out);
}

// Round 8
// 386.681 us; speedup vs baseline: 1.0195x; 1.0195x over previous
//
#include <hip/hip_runtime.h>
#include <math.h>

typedef __attribute__((ext_vector_type(8))) short bf16x8;
typedef __attribute__((ext_vector_type(4))) float f32x4;
typedef __attribute__((ext_vector_type(4))) unsigned short u16x4;

#define NB 64
#define NS 4096
#define NH 512
#define NE 1024
#define APITCH 80  // 64B bf16 K-row + 16B pad: conflict-free b128 frag reads

__device__ __forceinline__ unsigned short f2bf(float f) {
  unsigned int u = __float_as_uint(f);
  u += 0x7fffu + ((u >> 16) & 1u);
  return (unsigned short)(u >> 16);
}

__device__ __forceinline__ float fast_tanh(float x) {
  float e = __expf(2.0f * x);
  return 1.0f - 2.0f * __builtin_amdgcn_rcpf(e + 1.0f);
}

// ---- pack W (f32 [512][1024]) into MFMA B-fragment order, bf16 ----
// chunk c = ((w*32 + kb)*4 + ni); lane l's 16B = W[w*64+ni*16+(l&15)][kb*32+(l>>4)*8 .. +7]
__global__ __launch_bounds__(256) void prep_b_kernel(const float* __restrict__ W,
                                                     unsigned short* __restrict__ Bp) {
  const int t = blockIdx.x * 256 + threadIdx.x;  // 0..65535
  const int lane = t & 63;
  const int ni = (t >> 6) & 3;
  const int kb = (t >> 8) & 31;
  const int w = t >> 13;
  const int col = w * 64 + ni * 16 + (lane & 15);
  const int k0 = kb * 32 + (lane >> 4) * 8;
  const float* src = W + col * NE + k0;
  float4 a = *(const float4*)src;
  float4 b = *(const float4*)(src + 4);
  union { bf16x8 v; unsigned short u[8]; } p;
  p.u[0] = f2bf(a.x); p.u[1] = f2bf(a.y); p.u[2] = f2bf(a.z); p.u[3] = f2bf(a.w);
  p.u[4] = f2bf(b.x); p.u[5] = f2bf(b.y); p.u[6] = f2bf(b.z); p.u[7] = f2bf(b.w);
  *(bf16x8*)(Bp + (long long)t * 8) = p.v;
}

// ---- prep: dec[b,h] = decoder_output[b,:] . W_s_w[h,:] + W_s_b[h] + W_h_b[h] ----
__global__ __launch_bounds__(512) void prep_dec_kernel(const float* __restrict__ dec,
                                                       const float* __restrict__ Wsw,
                                                       const float* __restrict__ Wsb,
                                                       const float* __restrict__ Whb,
                                                       float* __restrict__ decb) {
  int b = blockIdx.x;
  int h = threadIdx.x;
  const float4* dr = (const float4*)(dec + b * NH);
  const float4* wr = (const float4*)(Wsw + h * NH);
  float sum = Wsb[h] + Whb[h];
#pragma unroll 8
  for (int i = 0; i < NH / 4; ++i) {
    float4 a = dr[i], w = wr[i];
    sum += a.x * w.x + a.y * w.y + a.z * w.z + a.w * w.w;
  }
  decb[b * NH + h] = sum;
}

// ---- main: enc-proj GEMM (bf16 MFMA) + bias + tanh + v-dot -> scores ----
// BM=64, BN=512, BK=32, 512 thr / 8 waves, 2 blocks/CU.
// KEY CHANGE vs R6: af fragments for step t+1 are ds_read DURING step t's MFMA
// cluster (m201's read-ahead) via 4 rotating A-buffers -- ds_read latency off
// the barrier-to-barrier critical path. A staged 2 ahead via slotE/slotO.
__global__ __launch_bounds__(512, 4) void fused_main(const float* __restrict__ enc,
                                                     const unsigned short* __restrict__ Bp,
                                                     const float* __restrict__ decb,
                                                     const float* __restrict__ vw,
                                                     float* __restrict__ scores) {
  __shared__ __align__(16) char As[4][64 * APITCH];  // 4 x 5KB rotating bf16 tiles
  __shared__ float ssc[64];

  const int tid = threadIdx.x;
  const int lane = tid & 63;
  const int wave = tid >> 6;
  const int r15 = lane & 15;
  const int c4 = lane >> 4;
  const long long m0 = (long long)blockIdx.x * 64;

  if (tid < 64) ssc[tid] = 0.0f;

  // A staging: thread t -> row t>>3, f32-chunk t&7 (4 f32, coalesced 128B/row)
  const int arow = tid >> 3;
  const int achk = tid & 7;
  const float* aload = enc + (m0 + arow) * NE + achk * 4;
  const int awr = arow * APITCH + achk * 8;   // bf16 bytes
  const int rdb = r15 * APITCH + c4 * 16;     // frag read base (add mi*1280)

  const unsigned short* const bb = Bp + (long long)wave * 32 * 2048 + lane * 8;

  f32x4 acc[4][4];
#pragma unroll
  for (int mi = 0; mi < 4; ++mi)
#pragma unroll
    for (int ni = 0; ni < 4; ++ni) {
      f32x4 z = {0.f, 0.f, 0.f, 0.f};
      acc[mi][ni] = z;
    }

  // prologue: B(0)->bcur; A(0)->buf0, A(1)->buf1; A(2)->slotE; af(0) pre-read
  bf16x8 bcur[4];
#pragma unroll
  for (int ni = 0; ni < 4; ++ni) bcur[ni] = *(const bf16x8*)(bb + ni * 512);
  {
    float4 p0 = *(const float4*)(aload);
    float4 p1 = *(const float4*)(aload + 32);
    unsigned int w0, w1;
    asm("v_cvt_pk_bf16_f32 %0, %1, %2" : "=v"(w0) : "v"(p0.x), "v"(p0.y));
    asm("v_cvt_pk_bf16_f32 %0, %1, %2" : "=v"(w1) : "v"(p0.z), "v"(p0.w));
    uint2 wv0; wv0.x = w0; wv0.y = w1;
    *(uint2*)(&As[0][0] + awr) = wv0;
    asm("v_cvt_pk_bf16_f32 %0, %1, %2" : "=v"(w0) : "v"(p1.x), "v"(p1.y));
    asm("v_cvt_pk_bf16_f32 %0, %1, %2" : "=v"(w1) : "v"(p1.z), "v"(p1.w));
    uint2 wv1; wv1.x = w0; wv1.y = w1;
    *(uint2*)(&As[1][0] + awr) = wv1;
  }
  float4 slotE = *(const float4*)(aload + 64);  // A(2)
  float4 slotO;                                  // A(3), loaded at t=0
  asm volatile("s_waitcnt lgkmcnt(0)" ::: "memory");
  __builtin_amdgcn_s_barrier();

  bf16x8 af[4];
#pragma unroll
  for (int mi = 0; mi < 4; ++mi)
    af[mi] = *(const bf16x8*)(&As[0][0] + mi * 16 * APITCH + rdb);

#pragma unroll
  for (int t = 0; t < 32; ++t) {
    // load A(t+3) directly into the dead slot (parity (t+3)&1 == (t+1)&1)
    if (t < 29) {
      if (t & 1) slotE = *(const float4*)(aload + (t + 3) * 32);
      else       slotO = *(const float4*)(aload + (t + 3) * 32);
    }
    const char* Abn = &As[(t + 1) & 3][0];
    bf16x8 afn0, afn1, afn2, afn3;
    // af(t+1) read-ahead, staggered through the cluster (buffer complete since t-1)
    if (t < 31) afn0 = *(const bf16x8*)(Abn + rdb);
    __builtin_amdgcn_s_setprio(1);
#pragma unroll
    for (int ni = 0; ni < 4; ++ni)
      acc[0][ni] = __builtin_amdgcn_mfma_f32_16x16x32_bf16(af[0], bcur[ni], acc[0][ni], 0, 0, 0);
    if (t < 31) afn1 = *(const bf16x8*)(Abn + 1280 + rdb);
#pragma unroll
    for (int ni = 0; ni < 4; ++ni)
      acc[1][ni] = __builtin_amdgcn_mfma_f32_16x16x32_bf16(af[1], bcur[ni], acc[1][ni], 0, 0, 0);
    if (t < 31) afn2 = *(const bf16x8*)(Abn + 2560 + rdb);
#pragma unroll
    for (int ni = 0; ni < 4; ++ni)
      acc[2][ni] = __builtin_amdgcn_mfma_f32_16x16x32_bf16(af[2], bcur[ni], acc[2][ni], 0, 0, 0);
    if (t < 31) afn3 = *(const bf16x8*)(Abn + 3840 + rdb);
#pragma unroll
    for (int ni = 0; ni < 4; ++ni)
      acc[3][ni] = __builtin_amdgcn_mfma_f32_16x16x32_bf16(af[3], bcur[ni], acc[3][ni], 0, 0, 0);
    __builtin_amdgcn_s_setprio(0);
    // B(t+1) reload into same regs (WAR after cluster; compiler-counted vmcnt)
    if (t < 31) {
      const bf16x8* bp = (const bf16x8*)(bb + (t + 1) * 2048);
#pragma unroll
      for (int ni = 0; ni < 4; ++ni) bcur[ni] = bp[ni * 64];
    }
    // write A(t+2) from slot parity t&1 into buffer (t+2)&3
    if (t < 30) {
      float4 s = (t & 1) ? slotO : slotE;
      unsigned int w0, w1;
      asm("v_cvt_pk_bf16_f32 %0, %1, %2" : "=v"(w0) : "v"(s.x), "v"(s.y));
      asm("v_cvt_pk_bf16_f32 %0, %1, %2" : "=v"(w1) : "v"(s.z), "v"(s.w));
      uint2 wv; wv.x = w0; wv.y = w1;
      *(uint2*)(&As[(t + 2) & 3][0] + awr) = wv;
    }
    if (t < 31) {
      af[0] = afn0; af[1] = afn1; af[2] = afn2; af[3] = afn3;
      // fence write (and read-aheads, long done) before waves cross
      asm volatile("s_waitcnt lgkmcnt(0)" ::: "memory");
      __builtin_amdgcn_sched_barrier(0);
      __builtin_amdgcn_s_barrier();
    }
  }

  // epilogue: x = tanh(acc + dec[b,h]); score += v[h]*x
  // C/D layout: col = lane&15 (n), row = (lane>>4)*4 + j (m)
  const int bidx = (int)(m0 >> 12);  // blockIdx / 64
  const float* decrow = decb + bidx * NH;
  float part[4][4];
#pragma unroll
  for (int mi = 0; mi < 4; ++mi)
#pragma unroll
    for (int j = 0; j < 4; ++j) part[mi][j] = 0.f;

#pragma unroll
  for (int ni = 0; ni < 4; ++ni) {
    int col = (wave << 6) + ni * 16 + r15;
    float vc = vw[col];
    float dc = decrow[col];
#pragma unroll
    for (int mi = 0; mi < 4; ++mi)
#pragma unroll
      for (int j = 0; j < 4; ++j)
        part[mi][j] += vc * fast_tanh(acc[mi][ni][j] + dc);
  }
#pragma unroll
  for (int off = 1; off < 16; off <<= 1)
#pragma unroll
    for (int mi = 0; mi < 4; ++mi)
#pragma unroll
      for (int j = 0; j < 4; ++j)
        part[mi][j] += __shfl_xor(part[mi][j], off, 64);

  if (r15 == 0) {
#pragma unroll
    for (int mi = 0; mi < 4; ++mi)
#pragma unroll
      for (int j = 0; j < 4; ++j)
        atomicAdd(&ssc[mi * 16 + c4 * 4 + j], part[mi][j]);
  }
  __syncthreads();
  if (tid < 64) scores[m0 + tid] = ssc[tid];
}

// ---- masked softmax over S per batch row ----
__global__ __launch_bounds__(1024) void softmax_kernel(const float* __restrict__ scores,
                                                       const int* __restrict__ mask,
                                                       float* __restrict__ out) {
  __shared__ float rmax[16];
  __shared__ float rsum[16];
  const int b = blockIdx.x;
  const int t = threadIdx.x;
  const int wid = t >> 6;
  const int ln = t & 63;
  const int base = b * NS;

  float s[4];
  int mk[4];
  float mx = -INFINITY;
#pragma unroll
  for (int i = 0; i < 4; ++i) {
    int idx = t + i * 1024;
    s[i] = scores[base + idx];
    mk[i] = mask[base + idx];
    if (mk[i]) mx = fmaxf(mx, s[i]);
  }
#pragma unroll
  for (int off = 1; off < 64; off <<= 1) mx = fmaxf(mx, __shfl_xor(mx, off, 64));
  if (ln == 0) rmax[wid] = mx;
  __syncthreads();
  float m2 = -INFINITY;
#pragma unroll
  for (int i = 0; i < 16; ++i) m2 = fmaxf(m2, rmax[i]);

  float e[4];
  float sum = 0.f;
#pragma unroll
  for (int i = 0; i < 4; ++i) {
    e[i] = mk[i] ? expf(s[i] - m2) : 0.f;
    sum += e[i];
  }
#pragma unroll
  for (int off = 1; off < 64; off <<= 1) sum += __shfl_xor(sum, off, 64);
  if (ln == 0) rsum[wid] = sum;
  __syncthreads();
  float tot = 0.f;
#pragma unroll
  for (int i = 0; i < 16; ++i) tot += rsum[i];
  float inv = 1.0f / tot;
#pragma unroll
  for (int i = 0; i < 4; ++i) {
    int idx = t + i * 1024;
    out[base + idx] = e[i] * inv;
  }
}

extern "C" void kernel_launch(void* const* d_in, const int* in_sizes, int n_in,
                              void* d_out, int out_size, void* d_ws, size_t ws_size,
                              hipStream_t stream) {
  const float* dec = (const float*)d_in[0];   // [64,512]
  const float* enc = (const float*)d_in[1];   // [64,4096,1024]
  const int* mask = (const int*)d_in[2];      // [64,4096]
  const float* Whw = (const float*)d_in[3];   // [512,1024]
  const float* Whb = (const float*)d_in[4];   // [512]
  const float* Wsw = (const float*)d_in[5];   // [512,512]
  const float* Wsb = (const float*)d_in[6];   // [512]
  const float* vw = (const float*)d_in[7];    // [1,512]
  float* out = (float*)d_out;                 // [64,4096]

  unsigned short* Bp = (unsigned short*)d_ws;                         // 1 MB packed W
  float* decb = (float*)((char*)d_ws + (1 << 20));                    // 128 KB
  float* scoresb = (float*)((char*)d_ws + (1 << 20) + (128 << 10));   // 1 MB

  prep_b_kernel<<<dim3(256), dim3(256), 0, stream>>>(Whw, Bp);
  prep_dec_kernel<<<dim3(64), dim3(512), 0, stream>>>(dec, Wsw, Wsb, Whb, decb);
  fused_main<<<dim3(4096), dim3(512), 0, stream>>>(enc, Bp, decb, vw, scoresb);
  softmax_kernel<<<dim3(64), dim3(1024), 0, stream>>>(scoresb, mask, out);
}